// Round 1
// 159.693 us; speedup vs baseline: 1.0236x; 1.0236x over previous
//
#include <hip/hip_runtime.h>
#include <stdint.h>

// Sampler: B=128 rows, V=128000 vocab, K=20.
// Outputs (float32, concat): sampled[B], topk_logprobs[B*K], topk_indices[B*K].
//
// k1 (B*nsplit blocks x 256): streamed 2x-unrolled float4 (4 loads in flight);
//     per-lane raw exp2-sum (shared scaled arg); gumbel argmax with octet-
//     coalesced cheap screen (exact 2-log eval only on ~candidate records);
//     top-K via static threshold TAU=3.0 -> rare LDS candidate push.
//     Block->(row,split) remap mixes greedy/non-greedy rows per CU.
// k2 (B blocks x 64): merges wave records, exact top-K among candidates;
//     exact full-rescan fallback if any row has <K candidates or overflow.

#define KMAX 20
#define SAMPLING_EPS 1e-5f
#define TAU 3.0f
#define CPB 64    // candidate slots per k1 block
#define LOG2E 1.44269504f
#define SMARGIN 3e-4f   // screen margin, log2 units (covers all fp rounding)

static __device__ __forceinline__ float fexp2(float x) {
#if __has_builtin(__builtin_amdgcn_exp2f)
    return __builtin_amdgcn_exp2f(x);
#else
    return exp2f(x);
#endif
}

static __device__ __forceinline__ unsigned int ord32(float v) {
    unsigned int u = __float_as_uint(v);
    return u ^ ((unsigned int)((int)u >> 31) | 0x80000000u);
}
static __device__ __forceinline__ float unord32(unsigned int x) {
    unsigned int u = (x & 0x80000000u) ? (x ^ 0x80000000u) : ~x;
    return __uint_as_float(u);
}
static __device__ __forceinline__ unsigned long long shflxor64(unsigned long long v, int off) {
    int lo = __shfl_xor((int)(unsigned int)v, off, 64);
    int hi = __shfl_xor((int)(unsigned int)(v >> 32), off, 64);
    return ((unsigned long long)(unsigned int)hi << 32) | (unsigned int)lo;
}

// Gumbel exact eval: g = x*inv_t - log(-log u). Winner's u is ~1, where
// log1pf on the Sterbenz-exact (1-u) keeps relative accuracy.
static __device__ __forceinline__ float gumbel_exact(float x, float inv_t, float uu, float wm) {
    const float q = (uu > 0.984375f) ? -log1pf(-wm) : -__logf(uu);
    return x * inv_t - __logf(q);
}

// Provable upper bound of g*log2e: -log2(-log u) <= -log2(1-u) <= 127 - bits(1-u)*2^-23
// (classic bit-hack bound: log2(m*2^e) >= e + (m-1)). Tighter than the ilogb bound.
static __device__ __forceinline__ float gub_bound(float a, float uu) {
    return fmaf((float)__float_as_uint(1.0f - uu), -0x1p-23f, 127.0f + a);
}

__global__ __launch_bounds__(256, 6) void k1_partials(
        const float* __restrict__ logits, const float* __restrict__ u,
        const float* __restrict__ temp,
        unsigned int* __restrict__ wrec,     // per-wave {s, gval, gcol, pad}
        unsigned int* __restrict__ cntbuf,   // per-block raw candidate count
        uint2* __restrict__ candbuf,         // per-block CPB {val_bits, col}
        int V, int nsplit) {
    __shared__ int cnt;
    __shared__ uint2 cand[CPB];
    const int b = blockIdx.x;
    const int t = threadIdx.x;
    const int lane = t & 63;
    const int w = t >> 6;
    if (t == 0) cnt = 0;
    __syncthreads();

    // ---- block -> (row, split) remap: mixes greedy(r%4==0)/non-greedy rows
    // across any plausible dispatch stride (1, 8, 256). Bijective: (mb,sp) ->
    // (r,sp) is a bijection for gcd(61,nrows)=1; the xor-fold is a unit-
    // triangular GF(2) map for power-of-2 nrows.
    const int nrows = gridDim.x / nsplit;
    const int mb = b % nrows;
    const int sp = b / nrows;
    int r = (mb * 61 + (sp >> 1)) % nrows;
    if ((nrows & (nrows - 1)) == 0) r ^= (r >> 4);
    const int slot = r * nsplit + sp;         // storage slot (k2 layout)

    const float traw = temp[r];
    const bool greedy = traw < SAMPLING_EPS;
    const float inv_t = greedy ? 1.0f : (1.0f / traw);
    const float it2 = inv_t * LOG2E;          // scaled-arg in log2 units

    const int nf4 = V >> 2;
    const int per = (nf4 + nsplit - 1) / nsplit;
    const int f0 = sp * per;
    const int f1 = min(f0 + per, nf4);

    const float4* __restrict__ l4 = (const float4*)(logits + (size_t)r * V);
    const float4* __restrict__ u4 = (const float4*)(u + (size_t)r * V);

    float s0 = 0.0f, s1 = 0.0f, s2 = 0.0f, s3 = 0.0f;
    float gv = -INFINITY;
    int gcol = 0;

#define PUSH(xv, cc) do { \
        const int pi_ = atomicAdd(&cnt, 1); \
        if (pi_ < CPB) cand[pi_] = make_uint2(__float_as_uint(xv), (unsigned)(cc)); \
    } while (0)

    if (greedy) {
        int f = f0 + t;
        for (; f + 256 < f1; f += 512) {
            const float4 la = l4[f];
            const float4 lb = l4[f + 256];
            s0 += fexp2(la.x * it2); s1 += fexp2(la.y * it2);
            s2 += fexp2(la.z * it2); s3 += fexp2(la.w * it2);
            s0 += fexp2(lb.x * it2); s1 += fexp2(lb.y * it2);
            s2 += fexp2(lb.z * it2); s3 += fexp2(lb.w * it2);
            const float xm = fmaxf(fmaxf(fmaxf(la.x, la.y), fmaxf(la.z, la.w)),
                                   fmaxf(fmaxf(lb.x, lb.y), fmaxf(lb.z, lb.w)));
            if (xm >= TAU) {
                const int c0 = f << 2, c1 = (f + 256) << 2;
                if (la.x >= TAU) PUSH(la.x, c0);
                if (la.y >= TAU) PUSH(la.y, c0 + 1);
                if (la.z >= TAU) PUSH(la.z, c0 + 2);
                if (la.w >= TAU) PUSH(la.w, c0 + 3);
                if (lb.x >= TAU) PUSH(lb.x, c1);
                if (lb.y >= TAU) PUSH(lb.y, c1 + 1);
                if (lb.z >= TAU) PUSH(lb.z, c1 + 2);
                if (lb.w >= TAU) PUSH(lb.w, c1 + 3);
            }
        }
        for (; f < f1; f += 256) {
            const float4 la = l4[f];
            s0 += fexp2(la.x * it2); s1 += fexp2(la.y * it2);
            s2 += fexp2(la.z * it2); s3 += fexp2(la.w * it2);
            const float xm = fmaxf(fmaxf(la.x, la.y), fmaxf(la.z, la.w));
            if (xm >= TAU) {
                const int c0 = f << 2;
                if (la.x >= TAU) PUSH(la.x, c0);
                if (la.y >= TAU) PUSH(la.y, c0 + 1);
                if (la.z >= TAU) PUSH(la.z, c0 + 2);
                if (la.w >= TAU) PUSH(la.w, c0 + 3);
            }
        }
    } else {
        // prologue iteration: exact gumbel for every lane (seeds the screen)
        int f = f0 + t;
        if (f < f1) {
            const float4 la = l4[f];
            const float4 ua = u4[f];
            const int c0 = f << 2;
            s0 += fexp2(la.x * it2); s1 += fexp2(la.y * it2);
            s2 += fexp2(la.z * it2); s3 += fexp2(la.w * it2);
            { const float g = gumbel_exact(la.x, inv_t, ua.x, 1.0f - ua.x);
              if (g > gv) { gv = g; gcol = c0; } }
            { const float g = gumbel_exact(la.y, inv_t, ua.y, 1.0f - ua.y);
              if (g > gv) { gv = g; gcol = c0 + 1; } }
            { const float g = gumbel_exact(la.z, inv_t, ua.z, 1.0f - ua.z);
              if (g > gv) { gv = g; gcol = c0 + 2; } }
            { const float g = gumbel_exact(la.w, inv_t, ua.w, 1.0f - ua.w);
              if (g > gv) { gv = g; gcol = c0 + 3; } }
            const float xm = fmaxf(fmaxf(la.x, la.y), fmaxf(la.z, la.w));
            if (xm >= TAU) {
                if (la.x >= TAU) PUSH(la.x, c0);
                if (la.y >= TAU) PUSH(la.y, c0 + 1);
                if (la.z >= TAU) PUSH(la.z, c0 + 2);
                if (la.w >= TAU) PUSH(la.w, c0 + 3);
            }
        }
        // wave-wide seed for the screen (max of 256 exact gumbels), log2 units
        float gmax = gv;
        #pragma unroll
        for (int off = 1; off < 64; off <<= 1) gmax = fmaxf(gmax, __shfl_xor(gmax, off, 64));
        float gvs2 = fmaf(gmax, LOG2E, -SMARGIN);

#define EX(gj, xv, uu, cc) \
        if ((gj) > gvs2) { \
            const float wm_ = 1.0f - (uu); \
            const float ge_ = gumbel_exact(xv, inv_t, uu, wm_); \
            if (ge_ > gv) { gv = ge_; gcol = (cc); gvs2 = fmaf(ge_, LOG2E, -SMARGIN); } \
        }

        for (f += 256; f + 256 < f1; f += 512) {
            const float4 la = l4[f];
            const float4 lb = l4[f + 256];
            const float4 ua = u4[f];
            const float4 ub = u4[f + 256];
            const float a0 = la.x * it2, a1 = la.y * it2, a2 = la.z * it2, a3 = la.w * it2;
            const float a4 = lb.x * it2, a5 = lb.y * it2, a6 = lb.z * it2, a7 = lb.w * it2;
            s0 += fexp2(a0); s1 += fexp2(a1); s2 += fexp2(a2); s3 += fexp2(a3);
            s0 += fexp2(a4); s1 += fexp2(a5); s2 += fexp2(a6); s3 += fexp2(a7);
            const float g0 = gub_bound(a0, ua.x), g1 = gub_bound(a1, ua.y);
            const float g2 = gub_bound(a2, ua.z), g3 = gub_bound(a3, ua.w);
            const float g4 = gub_bound(a4, ub.x), g5 = gub_bound(a5, ub.y);
            const float g6 = gub_bound(a6, ub.z), g7 = gub_bound(a7, ub.w);
            const float gm = fmaxf(fmaxf(fmaxf(g0, g1), fmaxf(g2, g3)),
                                   fmaxf(fmaxf(g4, g5), fmaxf(g6, g7)));
            if (gm > gvs2) {
                const int c0 = f << 2, c1 = (f + 256) << 2;
                EX(g0, la.x, ua.x, c0)
                EX(g1, la.y, ua.y, c0 + 1)
                EX(g2, la.z, ua.z, c0 + 2)
                EX(g3, la.w, ua.w, c0 + 3)
                EX(g4, lb.x, ub.x, c1)
                EX(g5, lb.y, ub.y, c1 + 1)
                EX(g6, lb.z, ub.z, c1 + 2)
                EX(g7, lb.w, ub.w, c1 + 3)
            }
            const float xm = fmaxf(fmaxf(fmaxf(la.x, la.y), fmaxf(la.z, la.w)),
                                   fmaxf(fmaxf(lb.x, lb.y), fmaxf(lb.z, lb.w)));
            if (xm >= TAU) {
                const int c0 = f << 2, c1 = (f + 256) << 2;
                if (la.x >= TAU) PUSH(la.x, c0);
                if (la.y >= TAU) PUSH(la.y, c0 + 1);
                if (la.z >= TAU) PUSH(la.z, c0 + 2);
                if (la.w >= TAU) PUSH(la.w, c0 + 3);
                if (lb.x >= TAU) PUSH(lb.x, c1);
                if (lb.y >= TAU) PUSH(lb.y, c1 + 1);
                if (lb.z >= TAU) PUSH(lb.z, c1 + 2);
                if (lb.w >= TAU) PUSH(lb.w, c1 + 3);
            }
        }
        for (; f < f1; f += 256) {     // tail: single float4 step
            const float4 la = l4[f];
            const float4 ua = u4[f];
            const float a0 = la.x * it2, a1 = la.y * it2, a2 = la.z * it2, a3 = la.w * it2;
            s0 += fexp2(a0); s1 += fexp2(a1); s2 += fexp2(a2); s3 += fexp2(a3);
            const float g0 = gub_bound(a0, ua.x), g1 = gub_bound(a1, ua.y);
            const float g2 = gub_bound(a2, ua.z), g3 = gub_bound(a3, ua.w);
            const float gm = fmaxf(fmaxf(g0, g1), fmaxf(g2, g3));
            if (gm > gvs2) {
                const int c0 = f << 2;
                EX(g0, la.x, ua.x, c0)
                EX(g1, la.y, ua.y, c0 + 1)
                EX(g2, la.z, ua.z, c0 + 2)
                EX(g3, la.w, ua.w, c0 + 3)
            }
            const float xm = fmaxf(fmaxf(la.x, la.y), fmaxf(la.z, la.w));
            if (xm >= TAU) {
                const int c0 = f << 2;
                if (la.x >= TAU) PUSH(la.x, c0);
                if (la.y >= TAU) PUSH(la.y, c0 + 1);
                if (la.z >= TAU) PUSH(la.z, c0 + 2);
                if (la.w >= TAU) PUSH(la.w, c0 + 3);
            }
        }
#undef EX
    }
#undef PUSH

    // wave reductions: s sum, gumbel key max (val desc, col asc)
    float s = (s0 + s1) + (s2 + s3);
    #pragma unroll
    for (int off = 1; off < 64; off <<= 1) s += __shfl_xor(s, off, 64);
    unsigned long long gk = greedy ? 0ull
        : (((unsigned long long)ord32(gv) << 32) | (unsigned int)~(unsigned int)gcol);
    #pragma unroll
    for (int off = 1; off < 64; off <<= 1) {
        const unsigned long long o = shflxor64(gk, off);
        gk = (o > gk) ? o : gk;
    }
    if (lane == 0) {
        unsigned int* rp = wrec + (size_t)(slot * 4 + w) * 4;
        rp[0] = __float_as_uint(s);
        rp[1] = __float_as_uint(unord32((unsigned int)(gk >> 32)));
        rp[2] = ~(unsigned int)gk;
    }
    __syncthreads();
    const int c = cnt;
    if (t == 0) cntbuf[slot] = (unsigned)c;
    if (t < min(c, CPB)) candbuf[(size_t)slot * CPB + t] = cand[t];
}

__global__ __launch_bounds__(64) void k2_finalize(
        const unsigned int* __restrict__ wrec, const unsigned int* __restrict__ cntbuf,
        const uint2* __restrict__ candbuf, const float* __restrict__ logits,
        const float* __restrict__ temp, float* __restrict__ out,
        int B, int V, int K, int nsplit) {
    __shared__ unsigned long long kbuf[512];
    const int r = blockIdx.x;
    const int lane = threadIdx.x;
    const int NW = nsplit * 4;

    const float traw = temp[r];
    const bool greedy = traw < SAMPLING_EPS;
    const float tt = greedy ? 1.0f : traw;

    // merge per-wave records
    float s = 0.0f;
    unsigned long long gk = 0ull;
    if (lane < NW) {
        const unsigned int* rp = wrec + (size_t)(r * NW + lane) * 4;
        s = __uint_as_float(rp[0]);
        gk = ((unsigned long long)ord32(__uint_as_float(rp[1])) << 32) | (unsigned int)~rp[2];
    }
    #pragma unroll
    for (int off = 1; off < 64; off <<= 1) s += __shfl_xor(s, off, 64);
    #pragma unroll
    for (int off = 1; off < 64; off <<= 1) {
        const unsigned long long o = shflxor64(gk, off);
        gk = (o > gk) ? o : gk;
    }
    const float lS = logf(s);

    // gather candidates
    const int cnt_raw = (lane < nsplit) ? (int)cntbuf[r * nsplit + lane] : 0;
    const int cntc = min(cnt_raw, CPB);
    const bool ovf = __ballot(cnt_raw > CPB) != 0ull;
    int incl = cntc;
    #pragma unroll
    for (int d = 1; d < 64; d <<= 1) {
        const int o = __shfl_up(incl, d, 64);
        if (lane >= d) incl += o;
    }
    const int T = __shfl(incl, 63, 64);
    const int off0 = incl - cntc;

    unsigned long long keys[8];
    #pragma unroll
    for (int jj = 0; jj < 8; ++jj) keys[jj] = 0ull;

    if (!ovf && T >= K && T <= 512) {
        if (lane < nsplit) {
            const uint2* cb = candbuf + (size_t)(r * nsplit + lane) * CPB;
            for (int i = 0; i < cntc; ++i) {
                const uint2 e = cb[i];
                kbuf[off0 + i] = ((unsigned long long)ord32(__uint_as_float(e.x)) << 32)
                               | (unsigned int)~e.y;
            }
        }
        __syncthreads();
        #pragma unroll
        for (int jj = 0; jj < 8; ++jj) {
            const int idx = lane + 64 * jj;
            if (idx < T) keys[jj] = kbuf[idx];
        }
    } else {
        // exact fallback: wave-cooperative top-K full rescan (correctness insurance;
        // does not trigger with TAU=3.0 on N(0,1) rows)
        unsigned long long mykey = ((unsigned long long)0x007FFFFFu) << 32;
        unsigned long long minkey = mykey;
        float vmin = -INFINITY;
        const float* lr = logits + (size_t)r * V;
        for (int base = 0; base < V; base += 64) {
            const int i = base + lane;
            const float x = (i < V) ? lr[i] : -INFINITY;
            unsigned long long cm = __ballot((i < V) && (x >= vmin));
            while (cm) {
                const int src = (int)__builtin_ctzll(cm);
                cm &= cm - 1;
                const float cv = __shfl(x, src, 64);
                const int cc = __shfl(i, src, 64);
                const unsigned long long ck =
                    ((unsigned long long)ord32(cv) << 32) | (unsigned int)~(unsigned int)cc;
                if (ck > minkey) {
                    const bool own = (lane < K) && (mykey == minkey);
                    const unsigned long long om = __ballot(own);
                    if (lane == (int)__builtin_ctzll(om)) mykey = ck;
                    unsigned long long mk = (lane < K) ? mykey : ~0ull;
                    #pragma unroll
                    for (int o2 = 1; o2 < 64; o2 <<= 1) {
                        const unsigned long long o = shflxor64(mk, o2);
                        mk = (o < mk) ? o : mk;
                    }
                    minkey = mk;
                    vmin = unord32((unsigned int)(mk >> 32));
                }
            }
        }
        keys[0] = (lane < K) ? mykey : 0ull;
    }

    float* out_s  = out;
    float* out_lp = out + B;
    float* out_ix = out + B + (size_t)B * K;

    unsigned int top1 = 0;
    for (int k = 0; k < K; ++k) {
        unsigned long long loc = keys[0];
        #pragma unroll
        for (int jj = 1; jj < 8; ++jj) loc = (keys[jj] > loc) ? keys[jj] : loc;
        #pragma unroll
        for (int off = 1; off < 64; off <<= 1) {
            const unsigned long long o = shflxor64(loc, off);
            loc = (o > loc) ? o : loc;
        }
        #pragma unroll
        for (int jj = 0; jj < 8; ++jj) if (keys[jj] == loc) keys[jj] = 0ull;
        if (lane == 0) {
            const unsigned int col = ~(unsigned int)loc;
            const float v = unord32((unsigned int)(loc >> 32));
            out_lp[(size_t)r * K + k] = v / tt - lS;   // IEEE div matches ref's scaled
            out_ix[(size_t)r * K + k] = (float)col;
            if (k == 0) top1 = col;
        }
    }
    if (lane == 0) {
        out_s[r] = (float)(greedy ? top1 : (~(unsigned int)gk));
    }
}

extern "C" void kernel_launch(void* const* d_in, const int* in_sizes, int n_in,
                              void* d_out, int out_size, void* d_ws, size_t ws_size,
                              hipStream_t stream) {
    const float* logits = (const float*)d_in[0];
    const float* temp   = (const float*)d_in[1];
    const float* u      = (const float*)d_in[2];
    const int B = in_sizes[1];
    const int V = in_sizes[0] / B;
    int K = (out_size - B) / (2 * B);
    if (K > KMAX) K = KMAX;
    if (K < 1) K = 1;

    // pick largest split count whose ws footprint fits
    // footprint per block: wrec 4 waves*16B + cnt 4B + cand CPB*8B = 580 B
    int nsplit = 16;
    while (nsplit > 1 && (size_t)B * nsplit * 580 > ws_size) nsplit >>= 1;
    const int blocks = B * nsplit;

    unsigned int* wrec   = (unsigned int*)d_ws;              // blocks*4 waves * 4 u32
    unsigned int* cntbuf = wrec + (size_t)blocks * 16;       // blocks u32
    uint2*        candbf = (uint2*)(cntbuf + blocks);        // blocks * CPB uint2

    k1_partials<<<dim3(blocks), dim3(256), 0, stream>>>(
        logits, u, temp, wrec, cntbuf, candbf, V, nsplit);
    k2_finalize<<<dim3(B), dim3(64), 0, stream>>>(
        wrec, cntbuf, candbf, logits, temp, (float*)d_out, B, V, K, nsplit);
}